// Round 1
// 329.962 us; speedup vs baseline: 1.0725x; 1.0725x over previous
//
#include <hip/hip_runtime.h>
#include <hip/hip_bf16.h>
#include <math.h>

#define Bsz 2
#define Sq  2048
#define Dm  2048
#define Hn  16
#define KVn 4
#define HDn 128

typedef __attribute__((ext_vector_type(8))) short bf16x8;
typedef __attribute__((ext_vector_type(4))) float f32x4;

__device__ __forceinline__ short f2b(float f) {
    __hip_bfloat16 h = __float2bfloat16(f);
    return *reinterpret_cast<short*>(&h);
}
__device__ __forceinline__ float b2f(short s) {
    __hip_bfloat16 h = *reinterpret_cast<__hip_bfloat16*>(&s);
    return __bfloat162float(h);
}

// ---------------- fp32 -> bf16 elementwise (x) ----------------
__global__ __launch_bounds__(256) void f2b_kernel(
    const float* __restrict__ X, short* __restrict__ Y, int n4)
{
    int i = blockIdx.x * 256 + threadIdx.x;
    if (i >= n4) return;
    float4 v = ((const float4*)X)[i];
    short4 o;
    o.x = f2b(v.x); o.y = f2b(v.y); o.z = f2b(v.z); o.w = f2b(v.w);
    ((short4*)Y)[i] = o;
}

// ------------- ALL weights -> transposed bf16 in one launch -------------
// Output rows 0..3071 -> wqkvT (wq|wk|wv), rows 3072..5119 -> woT.
__global__ __launch_bounds__(256) void wconv_all_kernel(
    const float* __restrict__ wq, const float* __restrict__ wk,
    const float* __restrict__ wv, const float* __restrict__ wo,
    short* __restrict__ wqkvT, short* __restrict__ woT)
{
    __shared__ float t[32][33];
    const int n0 = blockIdx.x * 32;   // global output row
    const int k0 = blockIdx.y * 32;
    const int tx = threadIdx.x, ty = threadIdx.y;

    const float* W; int Nsec, nloc; short* dst;
    if (n0 < 2048)      { W = wq; Nsec = 2048; nloc = n0;        dst = wqkvT + (size_t)n0 * Dm; }
    else if (n0 < 2560) { W = wk; Nsec = 512;  nloc = n0 - 2048; dst = wqkvT + (size_t)n0 * Dm; }
    else if (n0 < 3072) { W = wv; Nsec = 512;  nloc = n0 - 2560; dst = wqkvT + (size_t)n0 * Dm; }
    else                { W = wo; Nsec = 2048; nloc = n0 - 3072; dst = woT + (size_t)(n0 - 3072) * Dm; }

#pragma unroll
    for (int r = 0; r < 4; ++r) {
        const int row = ty + 8 * r;
        t[row][tx] = W[(size_t)(k0 + row) * Nsec + nloc + tx];
    }
    __syncthreads();
#pragma unroll
    for (int r = 0; r < 4; ++r) {
        const int row = ty + 8 * r;
        dst[(size_t)row * Dm + k0 + tx] = f2b(t[tx][row]);
    }
}

// ---------------- bf16 MFMA GEMM: C(MxN) = A(MxK) * Bt(NxK)^T ----------------
// OT = short (bf16 out) or float.
template <typename OT>
__global__ __launch_bounds__(256) void gemm_bt_kernel(
    const short* __restrict__ A, const short* __restrict__ Bt,
    OT* __restrict__ C, int M, int N, int K)
{
    __shared__ __align__(16) short As[128 * 64];
    __shared__ __align__(16) short Bs[128 * 64];

    const int tid  = threadIdx.x;
    const int w    = tid >> 6;
    const int lane = tid & 63;
    const int m16  = lane & 15;
    const int g4   = lane >> 4;
    const int wm   = w >> 1, wn = w & 1;

    const int row0 = blockIdx.y * 128;
    const int col0 = blockIdx.x * 128;

    const short* Ab = A  + (size_t)row0 * K;
    const short* Bb = Bt + (size_t)col0 * K;

    const int trow = tid >> 3;
    const int soct = (tid & 7) ^ (trow & 7);

    f32x4 acc[4][4];
#pragma unroll
    for (int i = 0; i < 4; ++i)
#pragma unroll
        for (int j = 0; j < 4; ++j) acc[i][j] = (f32x4){0.f, 0.f, 0.f, 0.f};

    for (int k0 = 0; k0 < K; k0 += 64) {
#pragma unroll
        for (int r = 0; r < 4; ++r) {
            const short* gp = Ab + (size_t)(r * 32 + trow) * K + k0 + soct * 8;
            short* lp = &As[(size_t)(r * 256 + w * 64) * 8];
            __builtin_amdgcn_global_load_lds(
                (const __attribute__((address_space(1))) void*)gp,
                (__attribute__((address_space(3))) void*)lp, 16, 0, 0);
        }
#pragma unroll
        for (int r = 0; r < 4; ++r) {
            const short* gp = Bb + (size_t)(r * 32 + trow) * K + k0 + soct * 8;
            short* lp = &Bs[(size_t)(r * 256 + w * 64) * 8];
            __builtin_amdgcn_global_load_lds(
                (const __attribute__((address_space(1))) void*)gp,
                (__attribute__((address_space(3))) void*)lp, 16, 0, 0);
        }
        __syncthreads();

#pragma unroll
        for (int kc = 0; kc < 2; ++kc) {
            bf16x8 a[4], b[4];
            const int swz = (kc * 4 + g4) ^ (m16 & 7);
#pragma unroll
            for (int s = 0; s < 4; ++s) {
                const int rowA = wm * 64 + s * 16 + m16;
                a[s] = *(const bf16x8*)&As[rowA * 64 + swz * 8];
                const int rowB = wn * 64 + s * 16 + m16;
                b[s] = *(const bf16x8*)&Bs[rowB * 64 + swz * 8];
            }
#pragma unroll
            for (int i = 0; i < 4; ++i)
#pragma unroll
                for (int j = 0; j < 4; ++j)
                    acc[i][j] = __builtin_amdgcn_mfma_f32_16x16x32_bf16(
                        a[i], b[j], acc[i][j], 0, 0, 0);
        }
        __syncthreads();
    }

#pragma unroll
    for (int i = 0; i < 4; ++i) {
        const int mbase = row0 + wm * 64 + i * 16 + g4 * 4;
#pragma unroll
        for (int j = 0; j < 4; ++j) {
            const int n = col0 + wn * 64 + j * 16 + m16;
#pragma unroll
            for (int r = 0; r < 4; ++r) {
                if constexpr (sizeof(OT) == 2)
                    C[(size_t)(mbase + r) * N + n] = f2b(acc[i][j][r]);
                else
                    C[(size_t)(mbase + r) * N + n] = acc[i][j][r];
            }
        }
    }
}

// ------------- RoPE (Q and K in one launch) from bf16 C3 -> bf16 split layout -------------
// One thread per (b, s, i): the sincos is computed ONCE and reused for all 20
// heads (previously recomputed per head -> 20x redundant transcendentals).
// powf(theta, e) replaced by exp2f(e * log2(theta)).
__global__ __launch_bounds__(256) void rope_all_kernel(
    const short* __restrict__ C3b, short* __restrict__ Qb, short* __restrict__ Kb,
    const int* __restrict__ pos_ids, float qscale, int total)
{
    int idx = blockIdx.x * blockDim.x + threadIdx.x;
    if (idx >= total) return;
    const int i = idx & 63;
    int rest = idx >> 6;
    const int s = rest % Sq;
    const int b = rest / Sq;

    const int pos = pos_ids[b * Sq + s];
    const float e   = -(float)(2 * i) * (1.0f / (float)HDn);
    const float inv = exp2f(e * 18.931568569324174f);   // log2(500000)
    const float f   = (float)pos * inv;
    float sn, c;
    sincosf(f, &sn, &c);

    const short* src = C3b + ((size_t)(b * Sq + s)) * 3072;

    // Q heads (scaled)
#pragma unroll
    for (int h = 0; h < Hn; ++h) {
        const float x1 = b2f(src[h * HDn + i]);
        const float x2 = b2f(src[h * HDn + i + 64]);
        const size_t dst = (((size_t)b * Hn + h) * Sq + s) * HDn;
        Qb[dst + i]      = f2b((x1 * c - x2 * sn) * qscale);
        Qb[dst + i + 64] = f2b((x2 * c + x1 * sn) * qscale);
    }
    // K heads
#pragma unroll
    for (int h = 0; h < KVn; ++h) {
        const float x1 = b2f(src[2048 + h * HDn + i]);
        const float x2 = b2f(src[2048 + h * HDn + i + 64]);
        const size_t dst = (((size_t)b * KVn + h) * Sq + s) * HDn;
        Kb[dst + i]      = f2b(x1 * c - x2 * sn);
        Kb[dst + i + 64] = f2b(x2 * c + x1 * sn);
    }
}

// ------------- V region of bf16 C3 -> transposed (B,KV,HD,S) bf16 -------------
__global__ __launch_bounds__(256) void vconv_kernel(
    const short* __restrict__ C3b, short* __restrict__ Vt)
{
    __shared__ short t[32][34];
    const int bk = blockIdx.z;
    const int b  = bk >> 2, kv = bk & 3;
    const int s0 = blockIdx.x * 32;
    const int d0 = blockIdx.y * 32;
    const int tx = threadIdx.x, ty = threadIdx.y;

#pragma unroll
    for (int r = 0; r < 4; ++r) {
        const int row = ty + 8 * r;
        t[row][tx] = C3b[((size_t)(b * Sq + s0 + row)) * 3072 + 2560 + kv * HDn + d0 + tx];
    }
    __syncthreads();
#pragma unroll
    for (int r = 0; r < 4; ++r) {
        const int row = ty + 8 * r;
        Vt[((size_t)bk * HDn + d0 + row) * Sq + s0 + tx] = t[tx][row];
    }
}

// ------------- Block-cooperative MFMA flash attention, KQ orientation -------------
// 4 waves, 128 queries/block (two 16-q tiles per wave). Double-buffered 64-key
// chunks, one barrier per chunk. This round: T13 defer-max (skip O-rescale
// unless the tile max exceeds the running max by >8 in exp2-domain; P bounded
// by 2^8, safe in bf16) and T5 s_setprio(1) around the MFMA clusters.
__global__ __launch_bounds__(256, 2) void fattn_kernel(
    const short* __restrict__ Qb, const short* __restrict__ Kb,
    const short* __restrict__ Vtb, short* __restrict__ AOb)
{
    __shared__ __align__(16) short Ks[2][64 * 128];   // [buf][perm key][dim], oct-swizzled
    __shared__ __align__(16) short Vs[2][128 * 64];   // [buf][dim][key], oct-swizzled

    const int tid  = threadIdx.x;
    const int w    = tid >> 6;
    const int lane = tid & 63;
    const int m16  = lane & 15;
    const int g4   = lane >> 4;

    // balanced mapping: blocks i and i+256 have complementary q-tiles
    const int i    = blockIdx.x;
    const int half = i >> 8;
    const int k4   = i & 15;
    const int qt   = half ? k4 : 15 - k4;
    const int bh   = i >> 4;
    const int h    = bh & 15;
    const int b    = bh >> 4;
    const int kv   = h >> 2;
    const int q0   = qt << 7;
    const int qA   = q0 + w * 16;
    const int qB   = q0 + 64 + w * 16;

    bf16x8 qf[2][4];
#pragma unroll
    for (int j = 0; j < 2; ++j) {
        const short* qp = Qb + (((size_t)b * Hn + h) * Sq + (j ? qB : qA) + m16) * HDn + g4 * 8;
#pragma unroll
        for (int c = 0; c < 4; ++c) qf[j][c] = *(const bf16x8*)(qp + c * 32);
    }

    const short* kbase = Kb  + ((size_t)b * KVn + kv) * Sq * HDn;
    const short* vbase = Vtb + ((size_t)b * KVn + kv) * (size_t)HDn * Sq;

    // staging source pointers (loop-invariant part)
    const short* gpK[4];
    const short* gpV[4];
#pragma unroll
    for (int r = 0; r < 4; ++r) {
        const int ci = r * 256 + tid;
        const int R  = ci >> 4, o = ci & 15;          // LDS K row, oct
        const int hf = (R >> 5) & 1, Rl = R & 31;
        const int phys = hf * 32 + ((Rl >> 2) & 3) * 8 + ((Rl >> 4) & 1) * 4 + (Rl & 3);
        gpK[r] = kbase + (size_t)phys * HDn + (o ^ (R & 7)) * 8;
        const int d = ci >> 3, ov = ci & 7;           // V dim row, oct
        gpV[r] = vbase + (size_t)d * Sq + (ov ^ (d & 7)) * 8;
    }

    f32x4 Ot[2][8];
#pragma unroll
    for (int j = 0; j < 2; ++j)
#pragma unroll
        for (int t = 0; t < 8; ++t) Ot[j][t] = (f32x4){0.f, 0.f, 0.f, 0.f};
    float mcur[2] = {-1e30f, -1e30f}, lcur[2] = {0.f, 0.f};

    const int nch = qt * 2 + 2;

    auto stage = [&](int ch, int buf) {
        const size_t kt = (size_t)(ch << 6);
#pragma unroll
        for (int r = 0; r < 4; ++r) {
            const short* gp = gpK[r] + kt * HDn;
            short* lp = &Ks[buf][(size_t)(r * 256 + w * 64) * 8];
            __builtin_amdgcn_global_load_lds(
                (const __attribute__((address_space(1))) void*)gp,
                (__attribute__((address_space(3))) void*)lp, 16, 0, 0);
        }
#pragma unroll
        for (int r = 0; r < 4; ++r) {
            const short* gp = gpV[r] + kt;
            short* lp = &Vs[buf][(size_t)(r * 256 + w * 64) * 8];
            __builtin_amdgcn_global_load_lds(
                (const __attribute__((address_space(1))) void*)gp,
                (__attribute__((address_space(3))) void*)lp, 16, 0, 0);
        }
    };

    stage(0, 0);

    for (int ch = 0; ch < nch; ++ch) {
        const int cur = ch & 1;
        const int kt  = ch << 6;

        __syncthreads();   // loads for buf[cur] done; buf[cur^1] readers finished
        if (ch + 1 < nch) stage(ch + 1, cur ^ 1);

        const bool last  = (ch == nch - 1);
        const bool diag0 = (ch == nch - 2);

        const short* KsC = Ks[cur];
        const short* VsC = Vs[cur];

        // ---- scores for both tiles, sharing every K-frag read ----
        f32x4 sc0[4], sc1[4];
        __builtin_amdgcn_s_setprio(1);
#pragma unroll
        for (int f = 0; f < 4; ++f) {
            f32x4 a0 = (f32x4){0.f, 0.f, 0.f, 0.f};
            f32x4 a1 = (f32x4){0.f, 0.f, 0.f, 0.f};
            const int krow = f * 16 + m16;
#pragma unroll
            for (int c = 0; c < 4; ++c) {
                bf16x8 kf = *(const bf16x8*)&KsC[krow * 128 + (((c * 4 + g4) ^ (m16 & 7)) * 8)];
                a0 = __builtin_amdgcn_mfma_f32_16x16x32_bf16(kf, qf[0][c], a0, 0, 0, 0);
                a1 = __builtin_amdgcn_mfma_f32_16x16x32_bf16(kf, qf[1][c], a1, 0, 0, 0);
            }
            sc0[f] = a0; sc1[f] = a1;
        }
        __builtin_amdgcn_s_setprio(0);

        // ---- causal masks (phys key = kt + (f>>1)*32 + g4*8 + (f&1)*4 + i) ----
        if (diag0) {
            const int qg = qA + m16;
#pragma unroll
            for (int f = 0; f < 4; ++f)
#pragma unroll
                for (int ii = 0; ii < 4; ++ii) {
                    const int kg = kt + (f >> 1) * 32 + g4 * 8 + (f & 1) * 4 + ii;
                    if (kg > qg) sc0[f][ii] = -1e30f;
                }
        }
        if (last) {
            const int qg = qB + m16;
#pragma unroll
            for (int f = 0; f < 4; ++f)
#pragma unroll
                for (int ii = 0; ii < 4; ++ii) {
                    const int kg = kt + (f >> 1) * 32 + g4 * 8 + (f & 1) * 4 + ii;
                    if (kg > qg) sc1[f][ii] = -1e30f;
                }
        }

        // ---- online softmax per tile (T13 defer-max, THR=8 in exp2 domain) ----
        bf16x8 pf0[2], pf1[2];
        if (!last) {
            float mx = sc0[0][0];
#pragma unroll
            for (int f = 0; f < 4; ++f)
#pragma unroll
                for (int ii = 0; ii < 4; ++ii) mx = fmaxf(mx, sc0[f][ii]);
            mx = fmaxf(mx, __shfl_xor(mx, 16));
            mx = fmaxf(mx, __shfl_xor(mx, 32));
            if (!__all(mx <= mcur[0] + 8.0f)) {
                const float nm = fmaxf(mcur[0], mx);
                const float alpha = exp2f(mcur[0] - nm);
                mcur[0] = nm;
                lcur[0] *= alpha;
#pragma unroll
                for (int t = 0; t < 8; ++t)
#pragma unroll
                    for (int ii = 0; ii < 4; ++ii) Ot[0][t][ii] *= alpha;
            }
            float ps = 0.f;
#pragma unroll
            for (int f = 0; f < 4; ++f)
#pragma unroll
                for (int ii = 0; ii < 4; ++ii) {
                    sc0[f][ii] = exp2f(sc0[f][ii] - mcur[0]);
                    ps += sc0[f][ii];
                }
            ps += __shfl_xor(ps, 16);
            ps += __shfl_xor(ps, 32);
            lcur[0] += ps;
#pragma unroll
            for (int hf = 0; hf < 2; ++hf) {
                bf16x8 p;
#pragma unroll
                for (int j8 = 0; j8 < 8; ++j8)
                    p[j8] = f2b(j8 < 4 ? sc0[hf * 2][j8] : sc0[hf * 2 + 1][j8 - 4]);
                pf0[hf] = p;
            }
        }
        {
            float mx = sc1[0][0];
#pragma unroll
            for (int f = 0; f < 4; ++f)
#pragma unroll
                for (int ii = 0; ii < 4; ++ii) mx = fmaxf(mx, sc1[f][ii]);
            mx = fmaxf(mx, __shfl_xor(mx, 16));
            mx = fmaxf(mx, __shfl_xor(mx, 32));
            if (!__all(mx <= mcur[1] + 8.0f)) {
                const float nm = fmaxf(mcur[1], mx);
                const float alpha = exp2f(mcur[1] - nm);
                mcur[1] = nm;
                lcur[1] *= alpha;
#pragma unroll
                for (int t = 0; t < 8; ++t)
#pragma unroll
                    for (int ii = 0; ii < 4; ++ii) Ot[1][t][ii] *= alpha;
            }
            float ps = 0.f;
#pragma unroll
            for (int f = 0; f < 4; ++f)
#pragma unroll
                for (int ii = 0; ii < 4; ++ii) {
                    sc1[f][ii] = exp2f(sc1[f][ii] - mcur[1]);
                    ps += sc1[f][ii];
                }
            ps += __shfl_xor(ps, 16);
            ps += __shfl_xor(ps, 32);
            lcur[1] += ps;
#pragma unroll
            for (int hf = 0; hf < 2; ++hf) {
                bf16x8 p;
#pragma unroll
                for (int j8 = 0; j8 < 8; ++j8)
                    p[j8] = f2b(j8 < 4 ? sc1[hf * 2][j8] : sc1[hf * 2 + 1][j8 - 4]);
                pf1[hf] = p;
            }
        }

        // ---- PV: O^T[d][q] += V^T[d][k] * P[k][q] ----
        __builtin_amdgcn_s_setprio(1);
#pragma unroll
        for (int t = 0; t < 8; ++t) {
            const int d = t * 16 + m16;
            bf16x8 vfa = *(const bf16x8*)&VsC[d * 64 + ((g4 ^ (d & 7)) * 8)];
            bf16x8 vfb = *(const bf16x8*)&VsC[d * 64 + (((4 + g4) ^ (d & 7)) * 8)];
            if (!last) {
                Ot[0][t] = __builtin_amdgcn_mfma_f32_16x16x32_bf16(vfa, pf0[0], Ot[0][t], 0, 0, 0);
                Ot[0][t] = __builtin_amdgcn_mfma_f32_16x16x32_bf16(vfb, pf0[1], Ot[0][t], 0, 0, 0);
            }
            Ot[1][t] = __builtin_amdgcn_mfma_f32_16x16x32_bf16(vfa, pf1[0], Ot[1][t], 0, 0, 0);
            Ot[1][t] = __builtin_amdgcn_mfma_f32_16x16x32_bf16(vfb, pf1[1], Ot[1][t], 0, 0, 0);
        }
        __builtin_amdgcn_s_setprio(0);
    }

    // ---- epilogue ----
#pragma unroll
    for (int j = 0; j < 2; ++j) {
        const float inv = 1.0f / lcur[j];
        short* op = AOb + ((size_t)b * Sq + (j ? qB : qA) + m16) * (Hn * HDn) + h * HDn + g4 * 4;
#pragma unroll
        for (int t = 0; t < 8; ++t) {
            short4 o;
            o.x = f2b(Ot[j][t][0] * inv);
            o.y = f2b(Ot[j][t][1] * inv);
            o.z = f2b(Ot[j][t][2] * inv);
            o.w = f2b(Ot[j][t][3] * inv);
            *(short4*)(op + t * 16) = o;
        }
    }
}

extern "C" void kernel_launch(void* const* d_in, const int* in_sizes, int n_in,
                              void* d_out, int out_size, void* d_ws, size_t ws_size,
                              hipStream_t stream)
{
    const float* x   = (const float*)d_in[0];
    const float* wq  = (const float*)d_in[1];
    const float* wk  = (const float*)d_in[2];
    const float* wv  = (const float*)d_in[3];
    const float* wo  = (const float*)d_in[4];
    const int* pos   = (const int*)d_in[6];
    float* out = (float*)d_out;

    const int M = Bsz * Sq;            // 4096
    const size_t nX  = (size_t)M * Dm; // 8388608

    short* xb    = (short*)d_ws;
    short* wqkvT = xb + nX;                       // 3072 x 2048
    short* woT   = wqkvT + (size_t)3072 * Dm;     // 2048 x 2048
    short* C3b   = woT + (size_t)Dm * Dm;         // 4096 x 3072 bf16
    short* Qb    = C3b + (size_t)M * 3072;
    short* Kb    = Qb + nX;
    short* Vtb   = Kb + (size_t)Bsz * KVn * Sq * HDn;
    short* AOb   = Vtb + (size_t)Bsz * KVn * Sq * HDn;

    // --- conversions (2 launches) ---
    f2b_kernel<<<(nX / 4 + 255) / 256, 256, 0, stream>>>(x, xb, nX / 4);
    wconv_all_kernel<<<dim3(5120 / 32, Dm / 32), dim3(32, 8), 0, stream>>>(
        wq, wk, wv, wo, wqkvT, woT);

    // --- fused QKV projection -> bf16 C3 ---
    gemm_bt_kernel<short><<<dim3(3072 / 128, M / 128), 256, 0, stream>>>(
        xb, wqkvT, C3b, M, 3072, Dm);

    // --- RoPE (Q+K) in one launch: one thread per (b,s,i), 20 heads each ---
    {
        const float qscale = 0.08838834764831845f * 1.4426950408889634f;
        int tot = Bsz * Sq * 64;
        rope_all_kernel<<<(tot + 255) / 256, 256, 0, stream>>>(
            C3b, Qb, Kb, pos, qscale, tot);
    }
    vconv_kernel<<<dim3(Sq / 32, HDn / 32, Bsz * KVn), dim3(32, 8), 0, stream>>>(
        C3b, Vtb);

    // --- attention: one block per 128 q-rows, balanced order, dbuf staging ---
    fattn_kernel<<<Bsz * Hn * (Sq / 128), 256, 0, stream>>>(Qb, Kb, Vtb, AOb);

    // --- output projection (fp32 out) ---
    gemm_bt_kernel<float><<<dim3(Dm / 128, M / 128), 256, 0, stream>>>(
        AOb, woT, out, M, Dm, Dm);
}

// Round 2
// 323.832 us; speedup vs baseline: 1.0928x; 1.0189x over previous
//
#include <hip/hip_runtime.h>
#include <hip/hip_bf16.h>
#include <math.h>

#define Bsz 2
#define Sq  2048
#define Dm  2048
#define Hn  16
#define KVn 4
#define HDn 128

typedef __attribute__((ext_vector_type(8))) short bf16x8;
typedef __attribute__((ext_vector_type(4))) float f32x4;

__device__ __forceinline__ short f2b(float f) {
    __hip_bfloat16 h = __float2bfloat16(f);
    return *reinterpret_cast<short*>(&h);
}
__device__ __forceinline__ float b2f(short s) {
    __hip_bfloat16 h = *reinterpret_cast<__hip_bfloat16*>(&s);
    return __bfloat162float(h);
}

// ---------------- fp32 -> bf16 elementwise (x) ----------------
__global__ __launch_bounds__(256) void f2b_kernel(
    const float* __restrict__ X, short* __restrict__ Y, int n4)
{
    int i = blockIdx.x * 256 + threadIdx.x;
    if (i >= n4) return;
    float4 v = ((const float4*)X)[i];
    short4 o;
    o.x = f2b(v.x); o.y = f2b(v.y); o.z = f2b(v.z); o.w = f2b(v.w);
    ((short4*)Y)[i] = o;
}

// ------------- ALL weights -> transposed bf16 in one launch -------------
__global__ __launch_bounds__(256) void wconv_all_kernel(
    const float* __restrict__ wq, const float* __restrict__ wk,
    const float* __restrict__ wv, const float* __restrict__ wo,
    short* __restrict__ wqkvT, short* __restrict__ woT)
{
    __shared__ float t[32][33];
    const int n0 = blockIdx.x * 32;   // global output row
    const int k0 = blockIdx.y * 32;
    const int tx = threadIdx.x, ty = threadIdx.y;

    const float* W; int Nsec, nloc; short* dst;
    if (n0 < 2048)      { W = wq; Nsec = 2048; nloc = n0;        dst = wqkvT + (size_t)n0 * Dm; }
    else if (n0 < 2560) { W = wk; Nsec = 512;  nloc = n0 - 2048; dst = wqkvT + (size_t)n0 * Dm; }
    else if (n0 < 3072) { W = wv; Nsec = 512;  nloc = n0 - 2560; dst = wqkvT + (size_t)n0 * Dm; }
    else                { W = wo; Nsec = 2048; nloc = n0 - 3072; dst = woT + (size_t)(n0 - 3072) * Dm; }

#pragma unroll
    for (int r = 0; r < 4; ++r) {
        const int row = ty + 8 * r;
        t[row][tx] = W[(size_t)(k0 + row) * Nsec + nloc + tx];
    }
    __syncthreads();
#pragma unroll
    for (int r = 0; r < 4; ++r) {
        const int row = ty + 8 * r;
        dst[(size_t)row * Dm + k0 + tx] = f2b(t[tx][row]);
    }
}

// ---------------- bf16 MFMA GEMM: C(MxN) = A(MxK) * Bt(NxK)^T ----------------
template <typename OT>
__global__ __launch_bounds__(256) void gemm_bt_kernel(
    const short* __restrict__ A, const short* __restrict__ Bt,
    OT* __restrict__ C, int M, int N, int K)
{
    __shared__ __align__(16) short As[128 * 64];
    __shared__ __align__(16) short Bs[128 * 64];

    const int tid  = threadIdx.x;
    const int w    = tid >> 6;
    const int lane = tid & 63;
    const int m16  = lane & 15;
    const int g4   = lane >> 4;
    const int wm   = w >> 1, wn = w & 1;

    const int row0 = blockIdx.y * 128;
    const int col0 = blockIdx.x * 128;

    const short* Ab = A  + (size_t)row0 * K;
    const short* Bb = Bt + (size_t)col0 * K;

    const int trow = tid >> 3;
    const int soct = (tid & 7) ^ (trow & 7);

    f32x4 acc[4][4];
#pragma unroll
    for (int i = 0; i < 4; ++i)
#pragma unroll
        for (int j = 0; j < 4; ++j) acc[i][j] = (f32x4){0.f, 0.f, 0.f, 0.f};

    for (int k0 = 0; k0 < K; k0 += 64) {
#pragma unroll
        for (int r = 0; r < 4; ++r) {
            const short* gp = Ab + (size_t)(r * 32 + trow) * K + k0 + soct * 8;
            short* lp = &As[(size_t)(r * 256 + w * 64) * 8];
            __builtin_amdgcn_global_load_lds(
                (const __attribute__((address_space(1))) void*)gp,
                (__attribute__((address_space(3))) void*)lp, 16, 0, 0);
        }
#pragma unroll
        for (int r = 0; r < 4; ++r) {
            const short* gp = Bb + (size_t)(r * 32 + trow) * K + k0 + soct * 8;
            short* lp = &Bs[(size_t)(r * 256 + w * 64) * 8];
            __builtin_amdgcn_global_load_lds(
                (const __attribute__((address_space(1))) void*)gp,
                (__attribute__((address_space(3))) void*)lp, 16, 0, 0);
        }
        __syncthreads();

#pragma unroll
        for (int kc = 0; kc < 2; ++kc) {
            bf16x8 a[4], b[4];
            const int swz = (kc * 4 + g4) ^ (m16 & 7);
#pragma unroll
            for (int s = 0; s < 4; ++s) {
                const int rowA = wm * 64 + s * 16 + m16;
                a[s] = *(const bf16x8*)&As[rowA * 64 + swz * 8];
                const int rowB = wn * 64 + s * 16 + m16;
                b[s] = *(const bf16x8*)&Bs[rowB * 64 + swz * 8];
            }
#pragma unroll
            for (int i = 0; i < 4; ++i)
#pragma unroll
                for (int j = 0; j < 4; ++j)
                    acc[i][j] = __builtin_amdgcn_mfma_f32_16x16x32_bf16(
                        a[i], b[j], acc[i][j], 0, 0, 0);
        }
        __syncthreads();
    }

#pragma unroll
    for (int i = 0; i < 4; ++i) {
        const int mbase = row0 + wm * 64 + i * 16 + g4 * 4;
#pragma unroll
        for (int j = 0; j < 4; ++j) {
            const int n = col0 + wn * 64 + j * 16 + m16;
#pragma unroll
            for (int r = 0; r < 4; ++r) {
                if constexpr (sizeof(OT) == 2)
                    C[(size_t)(mbase + r) * N + n] = f2b(acc[i][j][r]);
                else
                    C[(size_t)(mbase + r) * N + n] = acc[i][j][r];
            }
        }
    }
}

// ------------- RoPE (Q and K in one launch): one thread per (b,s,i) -------------
__global__ __launch_bounds__(256) void rope_all_kernel(
    const short* __restrict__ C3b, short* __restrict__ Qb, short* __restrict__ Kb,
    const int* __restrict__ pos_ids, float qscale, int total)
{
    int idx = blockIdx.x * blockDim.x + threadIdx.x;
    if (idx >= total) return;
    const int i = idx & 63;
    int rest = idx >> 6;
    const int s = rest % Sq;
    const int b = rest / Sq;

    const int pos = pos_ids[b * Sq + s];
    const float e   = -(float)(2 * i) * (1.0f / (float)HDn);
    const float inv = exp2f(e * 18.931568569324174f);   // log2(500000)
    const float f   = (float)pos * inv;
    float sn, c;
    sincosf(f, &sn, &c);

    const short* src = C3b + ((size_t)(b * Sq + s)) * 3072;

#pragma unroll
    for (int h = 0; h < Hn; ++h) {
        const float x1 = b2f(src[h * HDn + i]);
        const float x2 = b2f(src[h * HDn + i + 64]);
        const size_t dst = (((size_t)b * Hn + h) * Sq + s) * HDn;
        Qb[dst + i]      = f2b((x1 * c - x2 * sn) * qscale);
        Qb[dst + i + 64] = f2b((x2 * c + x1 * sn) * qscale);
    }
#pragma unroll
    for (int h = 0; h < KVn; ++h) {
        const float x1 = b2f(src[2048 + h * HDn + i]);
        const float x2 = b2f(src[2048 + h * HDn + i + 64]);
        const size_t dst = (((size_t)b * KVn + h) * Sq + s) * HDn;
        Kb[dst + i]      = f2b(x1 * c - x2 * sn);
        Kb[dst + i + 64] = f2b(x2 * c + x1 * sn);
    }
}

// ------------- V region of bf16 C3 -> transposed (B,KV,HD,S) bf16 -------------
__global__ __launch_bounds__(256) void vconv_kernel(
    const short* __restrict__ C3b, short* __restrict__ Vt)
{
    __shared__ short t[32][34];
    const int bk = blockIdx.z;
    const int b  = bk >> 2, kv = bk & 3;
    const int s0 = blockIdx.x * 32;
    const int d0 = blockIdx.y * 32;
    const int tx = threadIdx.x, ty = threadIdx.y;

#pragma unroll
    for (int r = 0; r < 4; ++r) {
        const int row = ty + 8 * r;
        t[row][tx] = C3b[((size_t)(b * Sq + s0 + row)) * 3072 + 2560 + kv * HDn + d0 + tx];
    }
    __syncthreads();
#pragma unroll
    for (int r = 0; r < 4; ++r) {
        const int row = ty + 8 * r;
        Vt[((size_t)bk * HDn + d0 + row) * Sq + s0 + tx] = t[tx][row];
    }
}

// ------------- Block-cooperative MFMA flash attention, KQ orientation -------------
// UNIFORM-WORK version: q-tiles split to 64-row half-tiles (ht = 0..31, needing
// ht+1 key-chunks). Each block processes the complementary pair (31-p, p)
// sequentially -> every one of the 512 blocks does exactly 33 chunks. Both
// co-resident blocks per CU stay live to the end => 2 waves/SIMD sustained
// (was 1 wave/SIMD for the 30-chunk solo phase of the critical block).
// One 16-row MFMA tile per wave per chunk; dbuf staging carries across the
// job switch.
__global__ __launch_bounds__(256, 2) void fattn_kernel(
    const short* __restrict__ Qb, const short* __restrict__ Kb,
    const short* __restrict__ Vtb, short* __restrict__ AOb)
{
    __shared__ __align__(16) short Ks[2][64 * 128];   // [buf][perm key][dim], oct-swizzled
    __shared__ __align__(16) short Vs[2][128 * 64];   // [buf][dim][key], oct-swizzled

    const int tid  = threadIdx.x;
    const int w    = tid >> 6;
    const int lane = tid & 63;
    const int m16  = lane & 15;
    const int g4   = lane >> 4;

    // block -> (b, h, pair p)
    const int p  = blockIdx.x & 15;
    const int h  = (blockIdx.x >> 4) & 15;
    const int b  = blockIdx.x >> 8;
    const int kv = h >> 2;

    const int htA = 31 - p, htB = p;      // half-tile ids; nch = ht+1
    const int nchA = htA + 1, nchB = htB + 1;   // sums to 33 for every block
    const int qbA = htA << 6, qbB = htB << 6;

    // Q fragments for both jobs (static indexing via separate arrays)
    bf16x8 qfA[4], qfB[4];
    {
        const short* qpA = Qb + (((size_t)b * Hn + h) * Sq + qbA + w * 16 + m16) * HDn + g4 * 8;
        const short* qpB = Qb + (((size_t)b * Hn + h) * Sq + qbB + w * 16 + m16) * HDn + g4 * 8;
#pragma unroll
        for (int c = 0; c < 4; ++c) {
            qfA[c] = *(const bf16x8*)(qpA + c * 32);
            qfB[c] = *(const bf16x8*)(qpB + c * 32);
        }
    }

    const short* kbase = Kb  + ((size_t)b * KVn + kv) * Sq * HDn;
    const short* vbase = Vtb + ((size_t)b * KVn + kv) * (size_t)HDn * Sq;

    // staging source pointers (loop-invariant part)
    const short* gpK[4];
    const short* gpV[4];
#pragma unroll
    for (int r = 0; r < 4; ++r) {
        const int ci = r * 256 + tid;
        const int R  = ci >> 4, o = ci & 15;          // LDS K row, oct
        const int hf = (R >> 5) & 1, Rl = R & 31;
        const int phys = hf * 32 + ((Rl >> 2) & 3) * 8 + ((Rl >> 4) & 1) * 4 + (Rl & 3);
        gpK[r] = kbase + (size_t)phys * HDn + (o ^ (R & 7)) * 8;
        const int d = ci >> 3, ov = ci & 7;           // V dim row, oct
        gpV[r] = vbase + (size_t)d * Sq + (ov ^ (d & 7)) * 8;
    }

    auto stage = [&](int ktE, int buf) {
#pragma unroll
        for (int r = 0; r < 4; ++r) {
            const short* gp = gpK[r] + (size_t)ktE * HDn;
            short* lp = &Ks[buf][(size_t)(r * 256 + w * 64) * 8];
            __builtin_amdgcn_global_load_lds(
                (const __attribute__((address_space(1))) void*)gp,
                (__attribute__((address_space(3))) void*)lp, 16, 0, 0);
        }
#pragma unroll
        for (int r = 0; r < 4; ++r) {
            const short* gp = gpV[r] + ktE;
            short* lp = &Vs[buf][(size_t)(r * 256 + w * 64) * 8];
            __builtin_amdgcn_global_load_lds(
                (const __attribute__((address_space(1))) void*)gp,
                (__attribute__((address_space(3))) void*)lp, 16, 0, 0);
        }
    };

    f32x4 Ot[8];
#pragma unroll
    for (int t = 0; t < 8; ++t) Ot[t] = (f32x4){0.f, 0.f, 0.f, 0.f};
    float mcur = -1e30f, lcur = 0.f;
    int gpar = 0;

    auto run_job = [&](const bf16x8 (&qf)[4], int nch, int qb, bool lastJob) {
        for (int ch = 0; ch < nch; ++ch) {
            const int cur = gpar & 1;
            gpar ^= 1;
            const int kt = ch << 6;

            __syncthreads();   // staging of buf[cur] complete; buf[cur^1] readers done
            if (ch + 1 < nch)      stage((ch + 1) << 6, cur ^ 1);
            else if (!lastJob)     stage(0, cur ^ 1);   // prefetch next job's chunk 0

            const bool diag = (ch == nch - 1);
            const short* KsC = Ks[cur];
            const short* VsC = Vs[cur];

            // ---- scores: one 16q x 64k tile per wave ----
            f32x4 sc[4];
            __builtin_amdgcn_s_setprio(1);
#pragma unroll
            for (int f = 0; f < 4; ++f) {
                f32x4 a = (f32x4){0.f, 0.f, 0.f, 0.f};
                const int krow = f * 16 + m16;
#pragma unroll
                for (int c = 0; c < 4; ++c) {
                    bf16x8 kf = *(const bf16x8*)&KsC[krow * 128 + (((c * 4 + g4) ^ (m16 & 7)) * 8)];
                    a = __builtin_amdgcn_mfma_f32_16x16x32_bf16(kf, qf[c], a, 0, 0, 0);
                }
                sc[f] = a;
            }
            __builtin_amdgcn_s_setprio(0);

            // ---- causal mask (diagonal chunk only) ----
            if (diag) {
                const int qg = qb + w * 16 + m16;
#pragma unroll
                for (int f = 0; f < 4; ++f)
#pragma unroll
                    for (int ii = 0; ii < 4; ++ii) {
                        const int kg = kt + (f >> 1) * 32 + g4 * 8 + (f & 1) * 4 + ii;
                        if (kg > qg) sc[f][ii] = -1e30f;
                    }
            }

            // ---- online softmax (T13 defer-max, THR=8 in exp2 domain) ----
            float mx = sc[0][0];
#pragma unroll
            for (int f = 0; f < 4; ++f)
#pragma unroll
                for (int ii = 0; ii < 4; ++ii) mx = fmaxf(mx, sc[f][ii]);
            mx = fmaxf(mx, __shfl_xor(mx, 16));
            mx = fmaxf(mx, __shfl_xor(mx, 32));
            if (!__all(mx <= mcur + 8.0f)) {
                const float nm = fmaxf(mcur, mx);
                const float alpha = exp2f(mcur - nm);
                mcur = nm;
                lcur *= alpha;
#pragma unroll
                for (int t = 0; t < 8; ++t)
#pragma unroll
                    for (int ii = 0; ii < 4; ++ii) Ot[t][ii] *= alpha;
            }
            float ps = 0.f;
#pragma unroll
            for (int f = 0; f < 4; ++f)
#pragma unroll
                for (int ii = 0; ii < 4; ++ii) {
                    sc[f][ii] = exp2f(sc[f][ii] - mcur);
                    ps += sc[f][ii];
                }
            ps += __shfl_xor(ps, 16);
            ps += __shfl_xor(ps, 32);
            lcur += ps;

            bf16x8 pf[2];
#pragma unroll
            for (int hf = 0; hf < 2; ++hf) {
                bf16x8 pk;
#pragma unroll
                for (int j8 = 0; j8 < 8; ++j8)
                    pk[j8] = f2b(j8 < 4 ? sc[hf * 2][j8] : sc[hf * 2 + 1][j8 - 4]);
                pf[hf] = pk;
            }

            // ---- PV: O^T[d][q] += V^T[d][k] * P[k][q] ----
            __builtin_amdgcn_s_setprio(1);
#pragma unroll
            for (int t = 0; t < 8; ++t) {
                const int d = t * 16 + m16;
                bf16x8 vfa = *(const bf16x8*)&VsC[d * 64 + ((g4 ^ (d & 7)) * 8)];
                bf16x8 vfb = *(const bf16x8*)&VsC[d * 64 + (((4 + g4) ^ (d & 7)) * 8)];
                Ot[t] = __builtin_amdgcn_mfma_f32_16x16x32_bf16(vfa, pf[0], Ot[t], 0, 0, 0);
                Ot[t] = __builtin_amdgcn_mfma_f32_16x16x32_bf16(vfb, pf[1], Ot[t], 0, 0, 0);
            }
            __builtin_amdgcn_s_setprio(0);
        }
    };

    auto writeO = [&](int qb) {
        const float inv = 1.0f / lcur;
        short* op = AOb + ((size_t)(b * Sq + qb + w * 16 + m16)) * (Hn * HDn) + h * HDn + g4 * 4;
#pragma unroll
        for (int t = 0; t < 8; ++t) {
            short4 o;
            o.x = f2b(Ot[t][0] * inv);
            o.y = f2b(Ot[t][1] * inv);
            o.z = f2b(Ot[t][2] * inv);
            o.w = f2b(Ot[t][3] * inv);
            *(short4*)(op + t * 16) = o;
        }
    };

    stage(0, 0);
    run_job(qfA, nchA, qbA, false);
    writeO(qbA);
#pragma unroll
    for (int t = 0; t < 8; ++t) Ot[t] = (f32x4){0.f, 0.f, 0.f, 0.f};
    mcur = -1e30f; lcur = 0.f;
    run_job(qfB, nchB, qbB, true);
    writeO(qbB);
}

extern "C" void kernel_launch(void* const* d_in, const int* in_sizes, int n_in,
                              void* d_out, int out_size, void* d_ws, size_t ws_size,
                              hipStream_t stream)
{
    const float* x   = (const float*)d_in[0];
    const float* wq  = (const float*)d_in[1];
    const float* wk  = (const float*)d_in[2];
    const float* wv  = (const float*)d_in[3];
    const float* wo  = (const float*)d_in[4];
    const int* pos   = (const int*)d_in[6];
    float* out = (float*)d_out;

    const int M = Bsz * Sq;            // 4096
    const size_t nX  = (size_t)M * Dm; // 8388608

    short* xb    = (short*)d_ws;
    short* wqkvT = xb + nX;                       // 3072 x 2048
    short* woT   = wqkvT + (size_t)3072 * Dm;     // 2048 x 2048
    short* C3b   = woT + (size_t)Dm * Dm;         // 4096 x 3072 bf16
    short* Qb    = C3b + (size_t)M * 3072;
    short* Kb    = Qb + nX;
    short* Vtb   = Kb + (size_t)Bsz * KVn * Sq * HDn;
    short* AOb   = Vtb + (size_t)Bsz * KVn * Sq * HDn;

    // --- conversions (2 launches) ---
    f2b_kernel<<<(nX / 4 + 255) / 256, 256, 0, stream>>>(x, xb, nX / 4);
    wconv_all_kernel<<<dim3(5120 / 32, Dm / 32), dim3(32, 8), 0, stream>>>(
        wq, wk, wv, wo, wqkvT, woT);

    // --- fused QKV projection -> bf16 C3 ---
    gemm_bt_kernel<short><<<dim3(3072 / 128, M / 128), 256, 0, stream>>>(
        xb, wqkvT, C3b, M, 3072, Dm);

    // --- RoPE (Q+K) in one launch ---
    {
        const float qscale = 0.08838834764831845f * 1.4426950408889634f;
        int tot = Bsz * Sq * 64;
        rope_all_kernel<<<(tot + 255) / 256, 256, 0, stream>>>(
            C3b, Qb, Kb, pos, qscale, tot);
    }
    vconv_kernel<<<dim3(Sq / 32, HDn / 32, Bsz * KVn), dim3(32, 8), 0, stream>>>(
        C3b, Vtb);

    // --- attention: 512 uniform blocks (complementary half-tile pairs) ---
    fattn_kernel<<<Bsz * Hn * (Sq / 128), 256, 0, stream>>>(Qb, Kb, Vtb, AOb);

    // --- output projection (fp32 out) ---
    gemm_bt_kernel<float><<<dim3(Dm / 128, M / 128), 256, 0, stream>>>(
        AOb, woT, out, M, Dm, Dm);
}